// Round 13
// baseline (107.023 us; speedup 1.0000x reference)
//
#include <hip/hip_runtime.h>
#include <math.h>

// SSIM loss. 512-wide x 32-row strip per 512-thread block.
// R12/R13: BARRIER-FREE wave-synchronous staging. Each wave owns a private
// 74-col LDS region (64 own cols + 10 halo cols loaded redundantly by
// lanes 0..9). Intra-wave visibility via s_waitcnt lgkmcnt(0) (lockstep
// wave) -> zero __syncthreads in the main loop; 4096 independent waves.
// R11 measured VALUBusy 58% / occ 30% with 11 barriers and 2 blocks/CU:
// barrier convoy was the stall.
//  - f16-packed LDS entry {p01,p23,g01,g23}, 1 ds_read_b128/tap, pk_fma
//  - vertical conv: 14-slot shift window, f32 accum via fdot2
//  - unified tail group (rows 40,41 + zeros)
// R13 fix: R12 dropped the >=0 guard on the scatter weight index ->
// w[-1] OOB read packed garbage into slot 13's weight pair (absmax 0.23).

#define KW 11
#define HALF 5
#define STRIP 32
#define W 512
#define H 512
#define NT 512
#define NSLOT 14
#define WCOLS 76              // padded per-wave region (74 used)

static constexpr float kC1 = 0.0001f;
static constexpr float kC2 = 0.0009f;

typedef decltype(__builtin_amdgcn_cvt_pkrtz(0.f, 0.f)) half2v;

__device__ __forceinline__ float sgpr_f(float v) {
    return __int_as_float(__builtin_amdgcn_readfirstlane(__float_as_int(v)));
}
__device__ __forceinline__ int bci(half2v h) { return __builtin_bit_cast(int, h); }
__device__ __forceinline__ half2v bch(int i) { return __builtin_bit_cast(half2v, i); }

__global__ __launch_bounds__(NT, 2) void ssim_strip(
    const float* __restrict__ logits,
    const float* __restrict__ gts,
    const float* __restrict__ window,
    float* __restrict__ partial)
{
    __shared__ uint4 sq[2][NT / 64][WCOLS];
    __shared__ float red[NT / 64];

    const int x    = threadIdx.x;
    const int lane = x & 63;
    const int wid  = x >> 6;
    const int wb   = wid << 6;            // wave's first output col

    // 1D taps = row sums of 2D window (sum(g)=1); SGPR-hoisted.
    float w[KW];
#pragma unroll
    for (int k = 0; k < KW; ++k) {
        float s = 0.f;
#pragma unroll
        for (int j = 0; j < KW; ++j) s += window[k * KW + j];
        w[k] = sgpr_f(s);
    }

    // f16 tap pairs (wk,wk) for pk hconv, SGPR ints.
    int wk2i[KW];
#pragma unroll
    for (int k = 0; k < KW; ++k)
        wk2i[k] = __builtin_amdgcn_readfirstlane(
            bci(__builtin_amdgcn_cvt_pkrtz(w[k], w[k])));

    // f16 weight pairs for the vertical scatter (slot p, row-pairs):
    //   rows (0,1): (w[10-p], w[11-p])   p=0..11
    //   rows (2,3): (w[12-q], w[13-q])   q=2..13
    // FULL bounds guards on every index (R12 lesson: w[-1] OOB).
    int wpAi[12], wpBi[12];
#pragma unroll
    for (int p = 0; p < 12; ++p) {
        const float a0 = (10 - p >= 0 && 10 - p <= 10) ? w[10 - p] : 0.f;
        const float a1 = (11 - p >= 0 && 11 - p <= 10) ? w[11 - p] : 0.f;
        wpAi[p] = __builtin_amdgcn_readfirstlane(
            bci(__builtin_amdgcn_cvt_pkrtz(a0, a1)));
        const int q = p + 2;
        const float b0 = (12 - q >= 0 && 12 - q <= 10) ? w[12 - q] : 0.f;
        const float b1 = (13 - q >= 0 && 13 - q <= 10) ? w[13 - q] : 0.f;
        wpBi[p] = __builtin_amdgcn_readfirstlane(
            bci(__builtin_amdgcn_cvt_pkrtz(b0, b1)));
    }

    const int img = blockIdx.x >> 4;
    const int ty  = blockIdx.x & 15;
    const int y0  = ty * STRIP;
    const float* __restrict__ L = logits + (size_t)img * (H * W);
    const float* __restrict__ G = gts    + (size_t)img * (H * W);

    // primary column (always in-image); halo column for lanes 0..9
    const int xc_p = wb + lane;
    const bool hact = lane < 10;
    const int hidx = (lane < 5) ? lane : (64 + lane);      // 0..4, 69..73
    const int xch_raw = wb - 5 + hidx;
    const int xc_h = min(max(xch_raw, 0), W - 1);
    const float mkc_h = (xch_raw == xc_h) ? 1.f : 0.f;

    float P1[NSLOT], P2[NSLOT], PA[NSLOT], PB[NSLOT], PC[NSLOT];
#pragma unroll
    for (int i = 0; i < NSLOT; ++i) {
        P1[i] = 0.f; P2[i] = 0.f; PA[i] = 0.f; PB[i] = 0.f; PC[i] = 0.f;
    }

    // prefetch+preprocess into (dst_l, dst_g): masked sigmoid / masked gt
#define PF(dst_l, dst_g, j, rr_expr, COL, MKC)                                 \
    {                                                                          \
        const int row  = y0 - HALF + (rr_expr);                                \
        const int rowc = min(max(row, 0), H - 1);                              \
        const float mk = ((row == rowc) ? 1.f : 0.f) * (MKC);                  \
        const float lv = L[rowc * W + (COL)];                                  \
        const float gv = G[rowc * W + (COL)];                                  \
        dst_l[j] = mk * __builtin_amdgcn_rcpf(1.f + __expf(-lv));              \
        dst_g[j] = mk * gv;                                                    \
    }

    float pl[4], pgv[4], hl[4], hg[4];
#pragma unroll
    for (int j = 0; j < 4; ++j) PF(pl, pgv, j, j, xc_p, 1.f)
    if (hact) {
#pragma unroll
        for (int j = 0; j < 4; ++j) PF(hl, hg, j, j, xc_h, mkc_h)
    }

    float acc = 0.f;

#pragma unroll 2
    for (int g = 0; g <= 10; ++g) {
        const int b = g & 1;

        // ---- stage group g (wave-private region; primary + halo) ----
        {
            uint4 q;
            q.x = (unsigned)bci(__builtin_amdgcn_cvt_pkrtz(pl[0],  pl[1]));
            q.y = (unsigned)bci(__builtin_amdgcn_cvt_pkrtz(pl[2],  pl[3]));
            q.z = (unsigned)bci(__builtin_amdgcn_cvt_pkrtz(pgv[0], pgv[1]));
            q.w = (unsigned)bci(__builtin_amdgcn_cvt_pkrtz(pgv[2], pgv[3]));
            sq[b][wid][lane + 5] = q;
        }
        if (hact) {
            uint4 q;
            q.x = (unsigned)bci(__builtin_amdgcn_cvt_pkrtz(hl[0], hl[1]));
            q.y = (unsigned)bci(__builtin_amdgcn_cvt_pkrtz(hl[2], hl[3]));
            q.z = (unsigned)bci(__builtin_amdgcn_cvt_pkrtz(hg[0], hg[1]));
            q.w = (unsigned)bci(__builtin_amdgcn_cvt_pkrtz(hg[2], hg[3]));
            sq[b][wid][hidx] = q;
        }

        // ---- prefetch next group (hides global latency under compute) ----
        if (g < 9) {
#pragma unroll
            for (int j = 0; j < 4; ++j) PF(pl, pgv, j, 4 * (g + 1) + j, xc_p, 1.f)
            if (hact) {
#pragma unroll
                for (int j = 0; j < 4; ++j) PF(hl, hg, j, 4 * (g + 1) + j, xc_h, mkc_h)
            }
        } else if (g == 9) {
            PF(pl, pgv, 0, 40, xc_p, 1.f)
            PF(pl, pgv, 1, 41, xc_p, 1.f)
            pl[2] = 0.f; pl[3] = 0.f; pgv[2] = 0.f; pgv[3] = 0.f;
            if (hact) {
                PF(hl, hg, 0, 40, xc_h, mkc_h)
                PF(hl, hg, 1, 41, xc_h, mkc_h)
                hl[2] = 0.f; hl[3] = 0.f; hg[2] = 0.f; hg[3] = 0.f;
            }
        }

        // wave-synchronous: ds_writes complete before any lane's reads
        asm volatile("s_waitcnt lgkmcnt(0)" ::: "memory");

        // ---- packed-f16 horizontal conv: 11 b128 reads, pk math ----
        const half2v hz = bch(0);
        half2v h1a = hz, h1b = hz, h2a = hz, h2b = hz;
        half2v hAa = hz, hAb = hz, hBa = hz, hBb = hz;
        half2v hCa = hz, hCb = hz;
#pragma unroll
        for (int k = 0; k < KW; ++k) {
            const uint4 q = sq[b][wid][lane + k];
            const half2v p01 = bch((int)q.x), p23 = bch((int)q.y);
            const half2v g01 = bch((int)q.z), g23 = bch((int)q.w);
            const half2v wk2 = bch(wk2i[k]);
            h1a += wk2 * p01;          h1b += wk2 * p23;
            h2a += wk2 * g01;          h2b += wk2 * g23;
            hAa += wk2 * (p01 * p01);  hAb += wk2 * (p23 * p23);
            hBa += wk2 * (g01 * g01);  hBb += wk2 * (g23 * g23);
            hCa += wk2 * (p01 * g01);  hCb += wk2 * (p23 * g23);
        }

        // ---- vertical scatter via fdot2 (f32 accumulators) ----
#pragma unroll
        for (int p = 0; p < 12; ++p) {
            const half2v wa = bch(wpAi[p]);
            P1[p] = __builtin_amdgcn_fdot2(h1a, wa, P1[p], false);
            P2[p] = __builtin_amdgcn_fdot2(h2a, wa, P2[p], false);
            PA[p] = __builtin_amdgcn_fdot2(hAa, wa, PA[p], false);
            PB[p] = __builtin_amdgcn_fdot2(hBa, wa, PB[p], false);
            PC[p] = __builtin_amdgcn_fdot2(hCa, wa, PC[p], false);
        }
#pragma unroll
        for (int p = 2; p < 14; ++p) {
            const half2v wb2 = bch(wpBi[p - 2]);
            P1[p] = __builtin_amdgcn_fdot2(h1b, wb2, P1[p], false);
            P2[p] = __builtin_amdgcn_fdot2(h2b, wb2, P2[p], false);
            PA[p] = __builtin_amdgcn_fdot2(hAb, wb2, PA[p], false);
            PB[p] = __builtin_amdgcn_fdot2(hBb, wb2, PB[p], false);
            PC[p] = __builtin_amdgcn_fdot2(hCb, wb2, PC[p], false);
        }

        // ---- emit completed slots (oo = 4g-10+p), shift window by 4 ----
        const int oo0 = 4 * g - 10;
#pragma unroll
        for (int p = 0; p < 4; ++p) {
            const int oo = oo0 + p;
            if (oo >= 0 && oo < STRIP) {
                const float m1 = P1[p], m2 = P2[p];
                const float mu11 = m1 * m1, mu22 = m2 * m2, mu12 = m1 * m2;
                const float s11 = PA[p] - mu11;
                const float s22 = PB[p] - mu22;
                const float s12 = PC[p] - mu12;
                const float num = (2.f * mu12 + kC1) * (2.f * s12 + kC2);
                const float den = (mu11 + mu22 + kC1) * (s11 + s22 + kC2);
                acc += num * __builtin_amdgcn_rcpf(den);
            }
        }
#pragma unroll
        for (int i = 0; i < NSLOT - 4; ++i) {
            P1[i] = P1[i + 4]; P2[i] = P2[i + 4];
            PA[i] = PA[i + 4]; PB[i] = PB[i + 4]; PC[i] = PC[i + 4];
        }
#pragma unroll
        for (int i = NSLOT - 4; i < NSLOT; ++i) {
            P1[i] = 0.f; P2[i] = 0.f; PA[i] = 0.f; PB[i] = 0.f; PC[i] = 0.f;
        }
    }

    // ---- block reduction (single barrier in the whole kernel) ----
#pragma unroll
    for (int off = 32; off > 0; off >>= 1) acc += __shfl_xor(acc, off);
    if (lane == 0) red[wid] = acc;
    __syncthreads();
    if (x == 0) {
        float s = 0.f;
#pragma unroll
        for (int i = 0; i < NT / 64; ++i) s += red[i];
        partial[blockIdx.x] = s;
    }
#undef PF
}

__global__ __launch_bounds__(256) void ssim_finalize(
    const float* __restrict__ partial, int nparts, double inv_count,
    float* __restrict__ out)
{
    __shared__ double sd[256];
    const int tid = threadIdx.x;
    double s = 0.0;
    for (int i = tid; i < nparts; i += 256) s += (double)partial[i];
    sd[tid] = s;
    __syncthreads();
    for (int st = 128; st > 0; st >>= 1) {
        if (tid < st) sd[tid] += sd[tid + st];
        __syncthreads();
    }
    if (tid == 0) out[0] = (float)(1.0 - sd[0] * inv_count);
}

extern "C" void kernel_launch(void* const* d_in, const int* in_sizes, int n_in,
                              void* d_out, int out_size, void* d_ws, size_t ws_size,
                              hipStream_t stream) {
    const float* logits = (const float*)d_in[0];
    const float* gts    = (const float*)d_in[1];
    const float* window = (const float*)d_in[2];
    float* out = (float*)d_out;

    const int nimg = in_sizes[0] / (H * W);   // 32
    const int nblocks = nimg * (H / STRIP);   // 512

    float* partial = (float*)d_ws;

    ssim_strip<<<nblocks, NT, 0, stream>>>(logits, gts, window, partial);

    const double inv_count = 1.0 / ((double)nimg * H * W);
    ssim_finalize<<<1, 256, 0, stream>>>(partial, nblocks, inv_count, out);
}

// Round 14
// 53.117 us; speedup vs baseline: 2.0149x; 2.0149x over previous
//
#include <hip/hip_runtime.h>
#include <math.h>

// SSIM loss. R14: one WAVE per block (64 threads), zero barriers.
// Each wave stages 64 cols (own LDS, f16-packed) and emits the 54 interior
// output cols; windows overlap by 10 (grid: 32 img x 16 strips x 10 windows
// = 5120 single-wave blocks). Intra-wave LDS visibility via lgkmcnt(0)
// (R13-proven). ONE prefetch path per lane (R13's dual halo path spilled:
// VGPR 128 + 217MB scratch; R5/R4 same lesson).
//  - f16-packed LDS entry {p01,p23,g01,g23}, 11 ds_read_b128/group, pk_fma
//  - vertical conv: 14-slot shift window, f32 accum via fdot2 (guards FULL,
//    R12 lesson: w[-1] OOB)
//  - lanes 54..63 compute garbage from zeroed pad entries; emit-guarded.

#define KW 11
#define HALF 5
#define STRIP 32
#define W 512
#define H 512
#define OUTW 54               // interior outputs per wave
#define NWIN 10               // ceil(512/54) windows across the row
#define NSLOT 14

static constexpr float kC1 = 0.0001f;
static constexpr float kC2 = 0.0009f;

typedef decltype(__builtin_amdgcn_cvt_pkrtz(0.f, 0.f)) half2v;

__device__ __forceinline__ float sgpr_f(float v) {
    return __int_as_float(__builtin_amdgcn_readfirstlane(__float_as_int(v)));
}
__device__ __forceinline__ int bci(half2v h) { return __builtin_bit_cast(int, h); }
__device__ __forceinline__ half2v bch(int i) { return __builtin_bit_cast(half2v, i); }

__global__ __launch_bounds__(64, 4) void ssim_wave(
    const float* __restrict__ logits,
    const float* __restrict__ gts,
    const float* __restrict__ window,
    float* __restrict__ partial)
{
    __shared__ uint4 sq[2][80];   // 64 staged cols + 16 zero pad (reads by
                                  // lanes 54..63 land in 64..73)

    const int lane = threadIdx.x;

    // 1D taps = row sums of 2D window (sum(g)=1); SGPR-hoisted.
    float w[KW];
#pragma unroll
    for (int k = 0; k < KW; ++k) {
        float s = 0.f;
#pragma unroll
        for (int j = 0; j < KW; ++j) s += window[k * KW + j];
        w[k] = sgpr_f(s);
    }

    // f16 tap pairs (wk,wk) for pk hconv, SGPR ints.
    int wk2i[KW];
#pragma unroll
    for (int k = 0; k < KW; ++k)
        wk2i[k] = __builtin_amdgcn_readfirstlane(
            bci(__builtin_amdgcn_cvt_pkrtz(w[k], w[k])));

    // f16 weight pairs for the vertical scatter (slot p, row-pairs):
    //   rows (0,1): (w[10-p], w[11-p])   p=0..11
    //   rows (2,3): (w[12-q], w[13-q])   q=2..13
    // FULL bounds guards on every index (R12 lesson: w[-1] OOB).
    int wpAi[12], wpBi[12];
#pragma unroll
    for (int p = 0; p < 12; ++p) {
        const float a0 = (10 - p >= 0 && 10 - p <= 10) ? w[10 - p] : 0.f;
        const float a1 = (11 - p >= 0 && 11 - p <= 10) ? w[11 - p] : 0.f;
        wpAi[p] = __builtin_amdgcn_readfirstlane(
            bci(__builtin_amdgcn_cvt_pkrtz(a0, a1)));
        const int q = p + 2;
        const float b0 = (12 - q >= 0 && 12 - q <= 10) ? w[12 - q] : 0.f;
        const float b1 = (13 - q >= 0 && 13 - q <= 10) ? w[13 - q] : 0.f;
        wpBi[p] = __builtin_amdgcn_readfirstlane(
            bci(__builtin_amdgcn_cvt_pkrtz(b0, b1)));
    }

    // block decode: ((img*16)+ty)*NWIN + wi, wi fastest for L2 overlap reuse
    const int wi  = blockIdx.x % NWIN;
    const int st  = blockIdx.x / NWIN;
    const int img = st >> 4;
    const int ty  = st & 15;
    const int y0  = ty * STRIP;
    const float* __restrict__ L = logits + (size_t)img * (H * W);
    const float* __restrict__ G = gts    + (size_t)img * (H * W);

    // lane's staged column (clamped + masked outside image)
    const int xbase  = wi * OUTW - HALF;
    const int xc_raw = xbase + lane;
    const int xc     = min(max(xc_raw, 0), W - 1);
    const float mkc  = (xc_raw == xc) ? 1.f : 0.f;
    // emit bound: lane < maxl (covers both lane<54 and right image edge)
    const int maxl = min(OUTW, W - wi * OUTW);

    // zero the pad entries once (visible after first lgkmcnt(0))
    if (lane < 16) {
        sq[0][64 + lane] = make_uint4(0, 0, 0, 0);
        sq[1][64 + lane] = make_uint4(0, 0, 0, 0);
    }

    float P1[NSLOT], P2[NSLOT], PA[NSLOT], PB[NSLOT], PC[NSLOT];
#pragma unroll
    for (int i = 0; i < NSLOT; ++i) {
        P1[i] = 0.f; P2[i] = 0.f; PA[i] = 0.f; PB[i] = 0.f; PC[i] = 0.f;
    }

    // prefetch+preprocess: pl = masked sigmoid(logit), pgv = masked gt
    float pl[4], pgv[4];
#define PF(j, rr_expr)                                                         \
    {                                                                          \
        const int row  = y0 - HALF + (rr_expr);                                \
        const int rowc = min(max(row, 0), H - 1);                              \
        const float mk = ((row == rowc) ? 1.f : 0.f) * mkc;                    \
        const float lv = L[rowc * W + xc];                                     \
        const float gv = G[rowc * W + xc];                                     \
        pl[j]  = mk * __builtin_amdgcn_rcpf(1.f + __expf(-lv));                \
        pgv[j] = mk * gv;                                                      \
    }
#pragma unroll
    for (int j = 0; j < 4; ++j) PF(j, j)

    float acc = 0.f;

#pragma unroll 2
    for (int g = 0; g <= 10; ++g) {
        const int b = g & 1;

        // ---- stage group g: one b128 write per lane ----
        {
            uint4 q;
            q.x = (unsigned)bci(__builtin_amdgcn_cvt_pkrtz(pl[0],  pl[1]));
            q.y = (unsigned)bci(__builtin_amdgcn_cvt_pkrtz(pl[2],  pl[3]));
            q.z = (unsigned)bci(__builtin_amdgcn_cvt_pkrtz(pgv[0], pgv[1]));
            q.w = (unsigned)bci(__builtin_amdgcn_cvt_pkrtz(pgv[2], pgv[3]));
            sq[b][lane] = q;
        }

        // ---- prefetch next group (hides global latency under compute) ----
        if (g < 9) {
#pragma unroll
            for (int j = 0; j < 4; ++j) PF(j, 4 * (g + 1) + j)
        } else if (g == 9) {
            PF(0, 40)
            PF(1, 41)
            pl[2] = 0.f; pl[3] = 0.f; pgv[2] = 0.f; pgv[3] = 0.f;
        }

        // wave-synchronous: ds_writes complete before any lane's reads
        asm volatile("s_waitcnt lgkmcnt(0)" ::: "memory");

        // ---- packed-f16 horizontal conv: 11 b128 reads, pk math ----
        const half2v hz = bch(0);
        half2v h1a = hz, h1b = hz, h2a = hz, h2b = hz;
        half2v hAa = hz, hAb = hz, hBa = hz, hBb = hz;
        half2v hCa = hz, hCb = hz;
#pragma unroll
        for (int k = 0; k < KW; ++k) {
            const uint4 q = sq[b][lane + k];
            const half2v p01 = bch((int)q.x), p23 = bch((int)q.y);
            const half2v g01 = bch((int)q.z), g23 = bch((int)q.w);
            const half2v wk2 = bch(wk2i[k]);
            h1a += wk2 * p01;          h1b += wk2 * p23;
            h2a += wk2 * g01;          h2b += wk2 * g23;
            hAa += wk2 * (p01 * p01);  hAb += wk2 * (p23 * p23);
            hBa += wk2 * (g01 * g01);  hBb += wk2 * (g23 * g23);
            hCa += wk2 * (p01 * g01);  hCb += wk2 * (p23 * g23);
        }

        // ---- vertical scatter via fdot2 (f32 accumulators) ----
#pragma unroll
        for (int p = 0; p < 12; ++p) {
            const half2v wa = bch(wpAi[p]);
            P1[p] = __builtin_amdgcn_fdot2(h1a, wa, P1[p], false);
            P2[p] = __builtin_amdgcn_fdot2(h2a, wa, P2[p], false);
            PA[p] = __builtin_amdgcn_fdot2(hAa, wa, PA[p], false);
            PB[p] = __builtin_amdgcn_fdot2(hBa, wa, PB[p], false);
            PC[p] = __builtin_amdgcn_fdot2(hCa, wa, PC[p], false);
        }
#pragma unroll
        for (int p = 2; p < 14; ++p) {
            const half2v wb2 = bch(wpBi[p - 2]);
            P1[p] = __builtin_amdgcn_fdot2(h1b, wb2, P1[p], false);
            P2[p] = __builtin_amdgcn_fdot2(h2b, wb2, P2[p], false);
            PA[p] = __builtin_amdgcn_fdot2(hAb, wb2, PA[p], false);
            PB[p] = __builtin_amdgcn_fdot2(hBb, wb2, PB[p], false);
            PC[p] = __builtin_amdgcn_fdot2(hCb, wb2, PC[p], false);
        }

        // ---- emit completed slots (oo = 4g-10+p), shift window by 4 ----
        const int oo0 = 4 * g - 10;
#pragma unroll
        for (int p = 0; p < 4; ++p) {
            const int oo = oo0 + p;
            if (oo >= 0 && oo < STRIP && lane < maxl) {
                const float m1 = P1[p], m2 = P2[p];
                const float mu11 = m1 * m1, mu22 = m2 * m2, mu12 = m1 * m2;
                const float s11 = PA[p] - mu11;
                const float s22 = PB[p] - mu22;
                const float s12 = PC[p] - mu12;
                const float num = (2.f * mu12 + kC1) * (2.f * s12 + kC2);
                const float den = (mu11 + mu22 + kC1) * (s11 + s22 + kC2);
                acc += num * __builtin_amdgcn_rcpf(den);
            }
        }
#pragma unroll
        for (int i = 0; i < NSLOT - 4; ++i) {
            P1[i] = P1[i + 4]; P2[i] = P2[i + 4];
            PA[i] = PA[i + 4]; PB[i] = PB[i + 4]; PC[i] = PC[i + 4];
        }
#pragma unroll
        for (int i = NSLOT - 4; i < NSLOT; ++i) {
            P1[i] = 0.f; P2[i] = 0.f; PA[i] = 0.f; PB[i] = 0.f; PC[i] = 0.f;
        }
    }

    // ---- wave reduction (no barrier needed anywhere) ----
#pragma unroll
    for (int off = 32; off > 0; off >>= 1) acc += __shfl_xor(acc, off);
    if (lane == 0) partial[blockIdx.x] = acc;
#undef PF
}

__global__ __launch_bounds__(256) void ssim_finalize(
    const float* __restrict__ partial, int nparts, double inv_count,
    float* __restrict__ out)
{
    __shared__ double sd[256];
    const int tid = threadIdx.x;
    double s = 0.0;
    for (int i = tid; i < nparts; i += 256) s += (double)partial[i];
    sd[tid] = s;
    __syncthreads();
    for (int st = 128; st > 0; st >>= 1) {
        if (tid < st) sd[tid] += sd[tid + st];
        __syncthreads();
    }
    if (tid == 0) out[0] = (float)(1.0 - sd[0] * inv_count);
}

extern "C" void kernel_launch(void* const* d_in, const int* in_sizes, int n_in,
                              void* d_out, int out_size, void* d_ws, size_t ws_size,
                              hipStream_t stream) {
    const float* logits = (const float*)d_in[0];
    const float* gts    = (const float*)d_in[1];
    const float* window = (const float*)d_in[2];
    float* out = (float*)d_out;

    const int nimg = in_sizes[0] / (H * W);          // 32
    const int nblocks = nimg * 16 * NWIN;            // 5120 single-wave blocks

    float* partial = (float*)d_ws;

    ssim_wave<<<nblocks, 64, 0, stream>>>(logits, gts, window, partial);

    const double inv_count = 1.0 / ((double)nimg * H * W);
    ssim_finalize<<<1, 256, 0, stream>>>(partial, nblocks, inv_count, out);
}

// Round 15
// 41.299 us; speedup vs baseline: 2.5914x; 1.2861x over previous
//
#include <hip/hip_runtime.h>
#include <math.h>

// SSIM loss. 512-wide x 32-row strip per 512-thread block (R11 structure,
// best at 40.8us). R15: ONE change - drain-free barrier. __syncthreads()
// emits s_waitcnt vmcnt(0) lgkmcnt(0) + s_barrier: the vmcnt(0) forces the
// 8 just-issued prefetch loads to return from HBM before ANY wave passes,
// every group (11x, 8-wave convoy). Replace with lgkmcnt(0)+raw s_barrier:
// LDS writes visible, global prefetch stays in flight across the barrier
// and completes under compute (compiler inserts vmcnt waits before use).
//  - f16-packed LDS entry {p01,p23,g01,g23}, 1 ds_read_b128/tap, pk_fma
//  - vertical conv: 14-slot shift window, f32 accum via fdot2 (FULL guards,
//    R12 lesson: w[-1] OOB)
//  - unified tail group (rows 40,41 + zeros)
// History: R4/R5/R13 spills (runtime idx / VGPR cap / dual prefetch path);
// R14 wave-private: +25% work, +68% fetch -> slower. One prefetch path,
// (512,2) budget, static slot indices = the proven-safe combo.

#define KW 11
#define HALF 5
#define STRIP 32
#define W 512
#define H 512
#define NT 512
#define SCOLS (W + 2*HALF)    // 522
#define NSLOT 14

static constexpr float kC1 = 0.0001f;
static constexpr float kC2 = 0.0009f;

typedef decltype(__builtin_amdgcn_cvt_pkrtz(0.f, 0.f)) half2v;

__device__ __forceinline__ float sgpr_f(float v) {
    return __int_as_float(__builtin_amdgcn_readfirstlane(__float_as_int(v)));
}
__device__ __forceinline__ int bci(half2v h) { return __builtin_bit_cast(int, h); }
__device__ __forceinline__ half2v bch(int i) { return __builtin_bit_cast(half2v, i); }

__global__ __launch_bounds__(NT, 2) void ssim_strip(
    const float* __restrict__ logits,
    const float* __restrict__ gts,
    const float* __restrict__ window,
    float* __restrict__ partial)
{
    __shared__ uint4 sq[2][SCOLS];   // {p01,p23,g01,g23} f16-pair bits
    __shared__ float red[NT / 64];

    const int x = threadIdx.x;

    // 1D taps = row sums of 2D window (sum(g)=1); SGPR-hoisted.
    float w[KW];
#pragma unroll
    for (int k = 0; k < KW; ++k) {
        float s = 0.f;
#pragma unroll
        for (int j = 0; j < KW; ++j) s += window[k * KW + j];
        w[k] = sgpr_f(s);
    }

    // f16 tap pairs (wk,wk) for pk hconv, SGPR ints.
    int wk2i[KW];
#pragma unroll
    for (int k = 0; k < KW; ++k)
        wk2i[k] = __builtin_amdgcn_readfirstlane(
            bci(__builtin_amdgcn_cvt_pkrtz(w[k], w[k])));

    // f16 weight pairs for the vertical scatter (slot p, row-pairs):
    //   rows (0,1): (w[10-p], w[11-p])   p=0..11
    //   rows (2,3): (w[12-q], w[13-q])   q=2..13
    // FULL bounds guards on every index (R12 lesson: w[-1] OOB).
    int wpAi[12], wpBi[12];
#pragma unroll
    for (int p = 0; p < 12; ++p) {
        const float a0 = (10 - p >= 0 && 10 - p <= 10) ? w[10 - p] : 0.f;
        const float a1 = (11 - p >= 0 && 11 - p <= 10) ? w[11 - p] : 0.f;
        wpAi[p] = __builtin_amdgcn_readfirstlane(
            bci(__builtin_amdgcn_cvt_pkrtz(a0, a1)));
        const int q = p + 2;
        const float b0 = (12 - q >= 0 && 12 - q <= 10) ? w[12 - q] : 0.f;
        const float b1 = (13 - q >= 0 && 13 - q <= 10) ? w[13 - q] : 0.f;
        wpBi[p] = __builtin_amdgcn_readfirstlane(
            bci(__builtin_amdgcn_cvt_pkrtz(b0, b1)));
    }

    const int img = blockIdx.x >> 4;
    const int ty  = blockIdx.x & 15;
    const int y0  = ty * STRIP;
    const float* __restrict__ L = logits + (size_t)img * (H * W);
    const float* __restrict__ G = gts    + (size_t)img * (H * W);

    // zero halo columns once, both buffers
    if (x < 2 * HALF) {
        const int sc = (x < HALF) ? x : (W + x);
        sq[0][sc] = make_uint4(0, 0, 0, 0);
        sq[1][sc] = make_uint4(0, 0, 0, 0);
    }

    float P1[NSLOT], P2[NSLOT], PA[NSLOT], PB[NSLOT], PC[NSLOT];
#pragma unroll
    for (int i = 0; i < NSLOT; ++i) {
        P1[i] = 0.f; P2[i] = 0.f; PA[i] = 0.f; PB[i] = 0.f; PC[i] = 0.f;
    }

    // prefetch+preprocess: pl = masked sigmoid(logit), pgv = masked gt
    float pl[4], pgv[4];
#define PREFETCH_ROW(j, rr_expr)                                               \
    {                                                                          \
        const int row  = y0 - HALF + (rr_expr);                                \
        const int rowc = min(max(row, 0), H - 1);                              \
        const float mk = (row == rowc) ? 1.f : 0.f;                            \
        const float lv = L[rowc * W + x];                                      \
        const float gv = G[rowc * W + x];                                      \
        pl[j]  = mk * __builtin_amdgcn_rcpf(1.f + __expf(-lv));                \
        pgv[j] = mk * gv;                                                      \
    }
#pragma unroll
    for (int j = 0; j < 4; ++j) PREFETCH_ROW(j, j)

    float acc = 0.f;

#pragma unroll 2
    for (int g = 0; g <= 10; ++g) {
        const int b = g & 1;

        // ---- stage group g as f16 pairs: one b128 write ----
        {
            uint4 q;
            q.x = (unsigned)bci(__builtin_amdgcn_cvt_pkrtz(pl[0],  pl[1]));
            q.y = (unsigned)bci(__builtin_amdgcn_cvt_pkrtz(pl[2],  pl[3]));
            q.z = (unsigned)bci(__builtin_amdgcn_cvt_pkrtz(pgv[0], pgv[1]));
            q.w = (unsigned)bci(__builtin_amdgcn_cvt_pkrtz(pgv[2], pgv[3]));
            sq[b][x + HALF] = q;
        }

        // ---- prefetch next group (stays in flight across the barrier) ----
        if (g < 9) {
#pragma unroll
            for (int j = 0; j < 4; ++j) PREFETCH_ROW(j, 4 * (g + 1) + j)
        } else if (g == 9) {
            PREFETCH_ROW(0, 40)
            PREFETCH_ROW(1, 41)
            pl[2] = 0.f; pl[3] = 0.f; pgv[2] = 0.f; pgv[3] = 0.f;
        }

        // ---- drain-free barrier: LDS writes visible, vmcnt NOT drained ----
        asm volatile("s_waitcnt lgkmcnt(0)" ::: "memory");
        __builtin_amdgcn_s_barrier();
        __builtin_amdgcn_sched_barrier(0);

        // ---- packed-f16 horizontal conv: 11 b128 reads, pk math ----
        const half2v hz = bch(0);
        half2v h1a = hz, h1b = hz, h2a = hz, h2b = hz;
        half2v hAa = hz, hAb = hz, hBa = hz, hBb = hz;
        half2v hCa = hz, hCb = hz;
#pragma unroll
        for (int k = 0; k < KW; ++k) {
            const uint4 q = sq[b][x + k];
            const half2v p01 = bch((int)q.x), p23 = bch((int)q.y);
            const half2v g01 = bch((int)q.z), g23 = bch((int)q.w);
            const half2v wk2 = bch(wk2i[k]);
            h1a += wk2 * p01;          h1b += wk2 * p23;
            h2a += wk2 * g01;          h2b += wk2 * g23;
            hAa += wk2 * (p01 * p01);  hAb += wk2 * (p23 * p23);
            hBa += wk2 * (g01 * g01);  hBb += wk2 * (g23 * g23);
            hCa += wk2 * (p01 * g01);  hCb += wk2 * (p23 * g23);
        }

        // ---- vertical scatter via fdot2 (f32 accumulators) ----
#pragma unroll
        for (int p = 0; p < 12; ++p) {
            const half2v wa = bch(wpAi[p]);
            P1[p] = __builtin_amdgcn_fdot2(h1a, wa, P1[p], false);
            P2[p] = __builtin_amdgcn_fdot2(h2a, wa, P2[p], false);
            PA[p] = __builtin_amdgcn_fdot2(hAa, wa, PA[p], false);
            PB[p] = __builtin_amdgcn_fdot2(hBa, wa, PB[p], false);
            PC[p] = __builtin_amdgcn_fdot2(hCa, wa, PC[p], false);
        }
#pragma unroll
        for (int p = 2; p < 14; ++p) {
            const half2v wb2 = bch(wpBi[p - 2]);
            P1[p] = __builtin_amdgcn_fdot2(h1b, wb2, P1[p], false);
            P2[p] = __builtin_amdgcn_fdot2(h2b, wb2, P2[p], false);
            PA[p] = __builtin_amdgcn_fdot2(hAb, wb2, PA[p], false);
            PB[p] = __builtin_amdgcn_fdot2(hBb, wb2, PB[p], false);
            PC[p] = __builtin_amdgcn_fdot2(hCb, wb2, PC[p], false);
        }

        // ---- emit completed slots (oo = 4g-10+p), shift window by 4 ----
        const int oo0 = 4 * g - 10;
#pragma unroll
        for (int p = 0; p < 4; ++p) {
            const int oo = oo0 + p;
            if (oo >= 0 && oo < STRIP) {
                const float m1 = P1[p], m2 = P2[p];
                const float mu11 = m1 * m1, mu22 = m2 * m2, mu12 = m1 * m2;
                const float s11 = PA[p] - mu11;
                const float s22 = PB[p] - mu22;
                const float s12 = PC[p] - mu12;
                const float num = (2.f * mu12 + kC1) * (2.f * s12 + kC2);
                const float den = (mu11 + mu22 + kC1) * (s11 + s22 + kC2);
                acc += num * __builtin_amdgcn_rcpf(den);
            }
        }
#pragma unroll
        for (int i = 0; i < NSLOT - 4; ++i) {
            P1[i] = P1[i + 4]; P2[i] = P2[i + 4];
            PA[i] = PA[i + 4]; PB[i] = PB[i + 4]; PC[i] = PC[i + 4];
        }
#pragma unroll
        for (int i = NSLOT - 4; i < NSLOT; ++i) {
            P1[i] = 0.f; P2[i] = 0.f; PA[i] = 0.f; PB[i] = 0.f; PC[i] = 0.f;
        }
    }

    // ---- block reduction (full __syncthreads is fine here, once) ----
#pragma unroll
    for (int off = 32; off > 0; off >>= 1) acc += __shfl_xor(acc, off);
    if ((x & 63) == 0) red[x >> 6] = acc;
    __syncthreads();
    if (x == 0) {
        float s = 0.f;
#pragma unroll
        for (int i = 0; i < NT / 64; ++i) s += red[i];
        partial[blockIdx.x] = s;
    }
#undef PREFETCH_ROW
}

__global__ __launch_bounds__(256) void ssim_finalize(
    const float* __restrict__ partial, int nparts, double inv_count,
    float* __restrict__ out)
{
    __shared__ double sd[256];
    const int tid = threadIdx.x;
    double s = 0.0;
    for (int i = tid; i < nparts; i += 256) s += (double)partial[i];
    sd[tid] = s;
    __syncthreads();
    for (int st = 128; st > 0; st >>= 1) {
        if (tid < st) sd[tid] += sd[tid + st];
        __syncthreads();
    }
    if (tid == 0) out[0] = (float)(1.0 - sd[0] * inv_count);
}

extern "C" void kernel_launch(void* const* d_in, const int* in_sizes, int n_in,
                              void* d_out, int out_size, void* d_ws, size_t ws_size,
                              hipStream_t stream) {
    const float* logits = (const float*)d_in[0];
    const float* gts    = (const float*)d_in[1];
    const float* window = (const float*)d_in[2];
    float* out = (float*)d_out;

    const int nimg = in_sizes[0] / (H * W);   // 32
    const int nblocks = nimg * (H / STRIP);   // 512

    float* partial = (float*)d_ws;

    ssim_strip<<<nblocks, NT, 0, stream>>>(logits, gts, window, partial);

    const double inv_count = 1.0 / ((double)nimg * H * W);
    ssim_finalize<<<1, 256, 0, stream>>>(partial, nblocks, inv_count, out);
}

// Round 16
// 39.290 us; speedup vs baseline: 2.7239x; 1.0511x over previous
//
#include <hip/hip_runtime.h>
#include <math.h>

// SSIM loss. 512-wide x 32-row strip per 512-thread block (R11/R15 base).
// R16: fully-STATIC group instantiation (macro with literal G, 11 groups):
//  - NSLOT=16 ring, absolute slot = output_row & 15 -> all indices fold at
//    compile time (R4's runtime-g ring spilled; literal G is rule-20-safe)
//  - no window shift (saves 70 movs/group), zero-after-emit
//  - scatter statically pruned to valid rows (edge groups lose 75% of dot2)
//  - symmetric hconv: w[k]==w[10-k], pair taps -> 146 vs 176 ops/group
//  - emit guards constant-folded
// Lesson ledger: VALU-issue time (busy% x dur) tracks speed across all
// rounds; barriers/occupancy were dead ends (R8/R14/R15). Spill watchlist:
// one prefetch path, (512,2) budget, static indices only.

#define KW 11
#define HALF 5
#define STRIP 32
#define W 512
#define H 512
#define NT 512
#define SCOLS (W + 2*HALF)    // 522

static constexpr float kC1 = 0.0001f;
static constexpr float kC2 = 0.0009f;

typedef decltype(__builtin_amdgcn_cvt_pkrtz(0.f, 0.f)) half2v;

__device__ __forceinline__ float sgpr_f(float v) {
    return __int_as_float(__builtin_amdgcn_readfirstlane(__float_as_int(v)));
}
__device__ __forceinline__ int bci(half2v h) { return __builtin_bit_cast(int, h); }
__device__ __forceinline__ half2v bch(int i) { return __builtin_bit_cast(half2v, i); }

// static scatter ranges: output row oo = 4G-10+idx must lie in [0, 31]
#define A_LO(G) ((10 - 4*(G)) > 0 ? (10 - 4*(G)) : 0)
#define A_HI(G) ((41 - 4*(G)) < 11 ? (41 - 4*(G)) : 11)
#define B_LO(G) ((10 - 4*(G)) > 2 ? (10 - 4*(G)) : 2)
#define B_HI(G) ((41 - 4*(G)) < 13 ? (41 - 4*(G)) : 13)

__global__ __launch_bounds__(NT, 2) void ssim_strip(
    const float* __restrict__ logits,
    const float* __restrict__ gts,
    const float* __restrict__ window,
    float* __restrict__ partial)
{
    __shared__ uint4 sq[2][SCOLS];   // {p01,p23,g01,g23} f16-pair bits
    __shared__ float red[NT / 64];

    const int x = threadIdx.x;

    // 1D taps = row sums of 2D window (sum(g)=1); SGPR-hoisted.
    float w[KW];
#pragma unroll
    for (int k = 0; k < KW; ++k) {
        float s = 0.f;
#pragma unroll
        for (int j = 0; j < KW; ++j) s += window[k * KW + j];
        w[k] = sgpr_f(s);
    }

    // f16 tap pairs (wk,wk) for pk hconv, SGPR ints.
    int wk2i[KW];
#pragma unroll
    for (int k = 0; k < KW; ++k)
        wk2i[k] = __builtin_amdgcn_readfirstlane(
            bci(__builtin_amdgcn_cvt_pkrtz(w[k], w[k])));

    // f16 weight pairs for the vertical scatter:
    //   rows (4G,4G+1):   idx d -> (w[10-d], w[11-d])    (wpAi)
    //   rows (4G+2,4G+3): idx p -> (w[12-p], w[13-p])    (wpBi, p-2 indexed)
    // FULL bounds guards (R12 lesson: w[-1] OOB).
    int wpAi[12], wpBi[12];
#pragma unroll
    for (int p = 0; p < 12; ++p) {
        const float a0 = (10 - p >= 0 && 10 - p <= 10) ? w[10 - p] : 0.f;
        const float a1 = (11 - p >= 0 && 11 - p <= 10) ? w[11 - p] : 0.f;
        wpAi[p] = __builtin_amdgcn_readfirstlane(
            bci(__builtin_amdgcn_cvt_pkrtz(a0, a1)));
        const int q = p + 2;
        const float b0 = (12 - q >= 0 && 12 - q <= 10) ? w[12 - q] : 0.f;
        const float b1 = (13 - q >= 0 && 13 - q <= 10) ? w[13 - q] : 0.f;
        wpBi[p] = __builtin_amdgcn_readfirstlane(
            bci(__builtin_amdgcn_cvt_pkrtz(b0, b1)));
    }

    const int img = blockIdx.x >> 4;
    const int ty  = blockIdx.x & 15;
    const int y0  = ty * STRIP;
    const float* __restrict__ L = logits + (size_t)img * (H * W);
    const float* __restrict__ G = gts    + (size_t)img * (H * W);

    // zero halo columns once, both buffers
    if (x < 2 * HALF) {
        const int sc = (x < HALF) ? x : (W + x);
        sq[0][sc] = make_uint4(0, 0, 0, 0);
        sq[1][sc] = make_uint4(0, 0, 0, 0);
    }

    // 16-slot ring accumulators (all statically indexed)
    float P1[16], P2[16], PA[16], PB[16], PC[16];
#pragma unroll
    for (int i = 0; i < 16; ++i) {
        P1[i] = 0.f; P2[i] = 0.f; PA[i] = 0.f; PB[i] = 0.f; PC[i] = 0.f;
    }

    float pl[4], pgv[4];
#define PREFETCH_ROW(j, rr_expr)                                               \
    {                                                                          \
        const int row  = y0 - HALF + (rr_expr);                                \
        const int rowc = min(max(row, 0), H - 1);                              \
        const float mk = (row == rowc) ? 1.f : 0.f;                            \
        const float lv = L[rowc * W + x];                                      \
        const float gv = G[rowc * W + x];                                      \
        pl[j]  = mk * __builtin_amdgcn_rcpf(1.f + __expf(-lv));                \
        pgv[j] = mk * gv;                                                      \
    }
#pragma unroll
    for (int j = 0; j < 4; ++j) PREFETCH_ROW(j, j)

    float acc = 0.f;

#define SSIM_GROUP(GG)                                                         \
    {                                                                          \
        { /* stage rows 4G..4G+3 as f16 pairs */                               \
            uint4 q;                                                           \
            q.x = (unsigned)bci(__builtin_amdgcn_cvt_pkrtz(pl[0],  pl[1]));    \
            q.y = (unsigned)bci(__builtin_amdgcn_cvt_pkrtz(pl[2],  pl[3]));    \
            q.z = (unsigned)bci(__builtin_amdgcn_cvt_pkrtz(pgv[0], pgv[1]));   \
            q.w = (unsigned)bci(__builtin_amdgcn_cvt_pkrtz(pgv[2], pgv[3]));   \
            sq[(GG) & 1][x + HALF] = q;                                        \
        }                                                                      \
        if ((GG) < 9) {                                                        \
            _Pragma("unroll")                                                  \
            for (int j = 0; j < 4; ++j) PREFETCH_ROW(j, 4 * ((GG) + 1) + j)    \
        } else if ((GG) == 9) {                                                \
            PREFETCH_ROW(0, 40)                                                \
            PREFETCH_ROW(1, 41)                                                \
            pl[2] = 0.f; pl[3] = 0.f; pgv[2] = 0.f; pgv[3] = 0.f;              \
        }                                                                      \
        asm volatile("s_waitcnt lgkmcnt(0)" ::: "memory");                     \
        __builtin_amdgcn_s_barrier();                                          \
        __builtin_amdgcn_sched_barrier(0);                                     \
        const half2v hz = bch(0);                                              \
        half2v h1a = hz, h1b = hz, h2a = hz, h2b = hz;                         \
        half2v hAa = hz, hAb = hz, hBa = hz, hBb = hz;                         \
        half2v hCa = hz, hCb = hz;                                             \
        _Pragma("unroll")                                                      \
        for (int k = 0; k < 5; ++k) { /* symmetric tap pairs (k, 10-k) */      \
            const uint4 qa = sq[(GG) & 1][x + k];                              \
            const uint4 qb = sq[(GG) & 1][x + 10 - k];                         \
            const half2v wk2 = bch(wk2i[k]);                                   \
            const half2v pa0 = bch((int)qa.x), pb0 = bch((int)qb.x);           \
            const half2v pa1 = bch((int)qa.y), pb1 = bch((int)qb.y);           \
            const half2v ga0 = bch((int)qa.z), gb0 = bch((int)qb.z);           \
            const half2v ga1 = bch((int)qa.w), gb1 = bch((int)qb.w);           \
            h1a += wk2 * (pa0 + pb0);  h1b += wk2 * (pa1 + pb1);               \
            h2a += wk2 * (ga0 + gb0);  h2b += wk2 * (ga1 + gb1);               \
            hAa += wk2 * (pa0 * pa0 + pb0 * pb0);                              \
            hAb += wk2 * (pa1 * pa1 + pb1 * pb1);                              \
            hBa += wk2 * (ga0 * ga0 + gb0 * gb0);                              \
            hBb += wk2 * (ga1 * ga1 + gb1 * gb1);                              \
            hCa += wk2 * (pa0 * ga0 + pb0 * gb0);                              \
            hCb += wk2 * (pa1 * ga1 + pb1 * gb1);                              \
        }                                                                      \
        { /* center tap k=5 */                                                 \
            const uint4 qc = sq[(GG) & 1][x + 5];                              \
            const half2v wk2 = bch(wk2i[5]);                                   \
            const half2v pc0 = bch((int)qc.x), pc1 = bch((int)qc.y);           \
            const half2v gc0 = bch((int)qc.z), gc1 = bch((int)qc.w);           \
            h1a += wk2 * pc0;  h1b += wk2 * pc1;                               \
            h2a += wk2 * gc0;  h2b += wk2 * gc1;                               \
            hAa += wk2 * (pc0 * pc0);  hAb += wk2 * (pc1 * pc1);               \
            hBa += wk2 * (gc0 * gc0);  hBb += wk2 * (gc1 * gc1);               \
            hCa += wk2 * (pc0 * gc0);  hCb += wk2 * (pc1 * gc1);               \
        }                                                                      \
        _Pragma("unroll")                                                      \
        for (int d = 0; d < 12; ++d) { /* rows (4G,4G+1), pruned static */     \
            if (d >= A_LO(GG) && d <= A_HI(GG)) {                              \
                const int s = (4 * (GG) + 6 + d) & 15;                         \
                const half2v wa = bch(wpAi[d]);                                \
                P1[s] = __builtin_amdgcn_fdot2(h1a, wa, P1[s], false);         \
                P2[s] = __builtin_amdgcn_fdot2(h2a, wa, P2[s], false);         \
                PA[s] = __builtin_amdgcn_fdot2(hAa, wa, PA[s], false);         \
                PB[s] = __builtin_amdgcn_fdot2(hBa, wa, PB[s], false);         \
                PC[s] = __builtin_amdgcn_fdot2(hCa, wa, PC[s], false);         \
            }                                                                  \
        }                                                                      \
        _Pragma("unroll")                                                      \
        for (int p = 2; p < 14; ++p) { /* rows (4G+2,4G+3), pruned static */   \
            if (p >= B_LO(GG) && p <= B_HI(GG)) {                              \
                const int s = (4 * (GG) + 6 + p) & 15;                         \
                const half2v wb2 = bch(wpBi[p - 2]);                           \
                P1[s] = __builtin_amdgcn_fdot2(h1b, wb2, P1[s], false);        \
                P2[s] = __builtin_amdgcn_fdot2(h2b, wb2, P2[s], false);        \
                PA[s] = __builtin_amdgcn_fdot2(hAb, wb2, PA[s], false);        \
                PB[s] = __builtin_amdgcn_fdot2(hBb, wb2, PB[s], false);        \
                PC[s] = __builtin_amdgcn_fdot2(hCb, wb2, PC[s], false);        \
            }                                                                  \
        }                                                                      \
        _Pragma("unroll")                                                      \
        for (int p = 0; p < 4; ++p) { /* emit rows 4G-10+p, static guard */    \
            const int oo = 4 * (GG) - 10 + p;                                  \
            if (oo >= 0 && oo < STRIP) {                                       \
                const int s = oo & 15;                                         \
                const float m1 = P1[s], m2 = P2[s];                            \
                const float mu11 = m1 * m1, mu22 = m2 * m2, mu12 = m1 * m2;    \
                const float s11 = PA[s] - mu11;                                \
                const float s22 = PB[s] - mu22;                                \
                const float s12 = PC[s] - mu12;                                \
                const float num = (2.f * mu12 + kC1) * (2.f * s12 + kC2);      \
                const float den = (mu11 + mu22 + kC1) * (s11 + s22 + kC2);     \
                acc += num * __builtin_amdgcn_rcpf(den);                       \
                P1[s] = 0.f; P2[s] = 0.f;                                      \
                PA[s] = 0.f; PB[s] = 0.f; PC[s] = 0.f;                         \
            }                                                                  \
        }                                                                      \
    }

    SSIM_GROUP(0)
    SSIM_GROUP(1)
    SSIM_GROUP(2)
    SSIM_GROUP(3)
    SSIM_GROUP(4)
    SSIM_GROUP(5)
    SSIM_GROUP(6)
    SSIM_GROUP(7)
    SSIM_GROUP(8)
    SSIM_GROUP(9)
    SSIM_GROUP(10)

#undef SSIM_GROUP
#undef PREFETCH_ROW

    // ---- block reduction ----
#pragma unroll
    for (int off = 32; off > 0; off >>= 1) acc += __shfl_xor(acc, off);
    if ((x & 63) == 0) red[x >> 6] = acc;
    __syncthreads();
    if (x == 0) {
        float s = 0.f;
#pragma unroll
        for (int i = 0; i < NT / 64; ++i) s += red[i];
        partial[blockIdx.x] = s;
    }
}

__global__ __launch_bounds__(256) void ssim_finalize(
    const float* __restrict__ partial, int nparts, double inv_count,
    float* __restrict__ out)
{
    __shared__ double sd[256];
    const int tid = threadIdx.x;
    double s = 0.0;
    for (int i = tid; i < nparts; i += 256) s += (double)partial[i];
    sd[tid] = s;
    __syncthreads();
    for (int st = 128; st > 0; st >>= 1) {
        if (tid < st) sd[tid] += sd[tid + st];
        __syncthreads();
    }
    if (tid == 0) out[0] = (float)(1.0 - sd[0] * inv_count);
}

extern "C" void kernel_launch(void* const* d_in, const int* in_sizes, int n_in,
                              void* d_out, int out_size, void* d_ws, size_t ws_size,
                              hipStream_t stream) {
    const float* logits = (const float*)d_in[0];
    const float* gts    = (const float*)d_in[1];
    const float* window = (const float*)d_in[2];
    float* out = (float*)d_out;

    const int nimg = in_sizes[0] / (H * W);   // 32
    const int nblocks = nimg * (H / STRIP);   // 512

    float* partial = (float*)d_ws;

    ssim_strip<<<nblocks, NT, 0, stream>>>(logits, gts, window, partial);

    const double inv_count = 1.0 / ((double)nimg * H * W);
    ssim_finalize<<<1, 256, 0, stream>>>(partial, nblocks, inv_count, out);
}